// Round 5
// baseline (191.106 us; speedup 1.0000x reference)
//
#include <hip/hip_runtime.h>

// Head: k = x@Wk^T; q = k (source bug); wei = softmax(causal(q k^T / 8)); v = x@Wv^T; out = wei@v
// B=8, T=2048, C=1024, H=64. fp32 in/out, bf16 MFMA internally.
//
// R4 -> R5: barrier-free design. proj and attn load MFMA fragments DIRECTLY from
// global in the native lane layout (lane low = row, quad*8+j = k) -> no LDS tiles,
// no __syncthreads, no vmcnt(0) barrier drains. W/K/V are L1/L2-resident; x streams
// with full cacheline use (4 quads cover 128 B/row). Only P keeps a wave-private
// LDS round-trip (C-layout -> A-layout). proj: register ping-pong prefetch.

typedef __bf16 bf16;
typedef __bf16 bf16x4 __attribute__((ext_vector_type(4)));
typedef __bf16 bf16x8 __attribute__((ext_vector_type(8)));
typedef float  floatx4 __attribute__((ext_vector_type(4)));

#define T_LEN 2048
#define HEAD  64
#define CEMB  1024

static __device__ __forceinline__ bf16x8 cvt2(float4 a, float4 b) {
    bf16x8 r;
    r[0] = (bf16)a.x; r[1] = (bf16)a.y; r[2] = (bf16)a.z; r[3] = (bf16)a.w;
    r[4] = (bf16)b.x; r[5] = (bf16)b.y; r[6] = (bf16)b.z; r[7] = (bf16)b.w;
    return r;
}

// ---------------- Kernel 0: W fp32 -> bf16, [Wk;Wv] concat as Wb[128][1024]
__global__ __launch_bounds__(256) void wconv_kernel(const float* __restrict__ Wk,
                                                    const float* __restrict__ Wv,
                                                    bf16* __restrict__ Wb) {
    int i = (blockIdx.x * 256 + threadIdx.x) * 4;   // grid 128 covers 131072
    const float* src = (i < 64 * 1024) ? (Wk + i) : (Wv + (i - 64 * 1024));
    float4 f = *(const float4*)src;
    bf16x4 v;
    v[0] = (bf16)f.x; v[1] = (bf16)f.y; v[2] = (bf16)f.z; v[3] = (bf16)f.w;
    *(bf16x4*)&Wb[i] = v;
}

// ---------------- Kernel 1: projection GEMM, barrier-free, no LDS.
// grid 512 x 256. Block = 32 rows; wave (mhalf,nhalf) = 16 rows x 64 cols.
// A-frag from x (fp32->bf16 inline), B-frag from Wb (bf16, L2-resident).
__global__ __launch_bounds__(256, 4) void proj_kernel(const float* __restrict__ x,
                                                      const bf16* __restrict__ Wb,
                                                      bf16* __restrict__ Kbuf,
                                                      bf16* __restrict__ Vt) {
    const int tid  = threadIdx.x;
    const int wave = tid >> 6;
    const int lane = tid & 63;
    const int quad = lane >> 4;
    const int low  = lane & 15;

    const int mhalf = wave >> 1;         // 16-row strip within block
    const int nhalf = wave & 1;          // 0 -> K cols, 1 -> V cols
    const long row0 = (long)blockIdx.x * 32 + mhalf * 16;

    const float* arow = x + (row0 + low) * CEMB + quad * 8;
    const bf16*  wrow = Wb + ((nhalf * 64) + low) * CEMB + quad * 8;

    floatx4 acc[4];
#pragma unroll
    for (int i = 0; i < 4; ++i) acc[i] = (floatx4){0.f, 0.f, 0.f, 0.f};

    float4 a0[2], a1[2];
    bf16x8 bfr[2][4];

    // prefetch chunk 0 into buf 0
    a0[0] = *(const float4*)(arow);
    a1[0] = *(const float4*)(arow + 4);
#pragma unroll
    for (int nt = 0; nt < 4; ++nt) bfr[0][nt] = *(const bf16x8*)(wrow + nt * 16 * CEMB);

#pragma unroll 2
    for (int c = 0; c < 32; ++c) {
        const int cur = c & 1, nxt = cur ^ 1;
        if (c < 31) {   // prefetch next chunk (in flight during cvt+MFMA)
            const int k0 = (c + 1) * 32;
            a0[nxt] = *(const float4*)(arow + k0);
            a1[nxt] = *(const float4*)(arow + k0 + 4);
#pragma unroll
            for (int nt = 0; nt < 4; ++nt)
                bfr[nxt][nt] = *(const bf16x8*)(wrow + nt * 16 * CEMB + k0);
        }
        bf16x8 af = cvt2(a0[cur], a1[cur]);
#pragma unroll
        for (int nt = 0; nt < 4; ++nt)
            acc[nt] = __builtin_amdgcn_mfma_f32_16x16x32_bf16(af, bfr[cur][nt], acc[nt], 0, 0, 0);
    }

    // epilogue: wave-uniform destination (nhalf=0 -> Kbuf[b][t][h], nhalf=1 -> Vt[b][h][t])
    const long bidx = row0 >> 11;
    const int  tl0  = (int)(row0 & 2047) + quad * 4;
    if (nhalf == 0) {
#pragma unroll
        for (int nt = 0; nt < 4; ++nt)
#pragma unroll
            for (int r = 0; r < 4; ++r)
                Kbuf[(bidx * T_LEN + tl0 + r) * HEAD + nt * 16 + low] = (bf16)acc[nt][r];
    } else {
#pragma unroll
        for (int nt = 0; nt < 4; ++nt)
#pragma unroll
            for (int r = 0; r < 4; ++r)
                Vt[(bidx * HEAD + nt * 16 + low) * T_LEN + tl0 + r] = (bf16)acc[nt][r];
    }
}

// ---------------- Kernel 2: attention partial, barrier-free. q=k, causal, scale 1/8,
// fixed-max softmax (p = exp(s/8), row sums via MFMA vs ones).
// blockIdx.x = ((b*32 + qb)*8 + c); chunk c: kv tiles j in {c, c+8, ...} <= qb.
// Q/K/V fragments direct from global (K,Vt are L2-resident); P via wave-private LDS.
__global__ __launch_bounds__(256) void attn_kernel(const bf16* __restrict__ Kbuf,
                                                   const bf16* __restrict__ Vt,
                                                   float* __restrict__ Opart,
                                                   float* __restrict__ lpart) {
    __shared__ __align__(16) bf16 Ps[4][16][72];   // per-wave private strip

    const int tid  = threadIdx.x;
    const int wave = tid >> 6;
    const int lane = tid & 63;
    const int quad = lane >> 4;
    const int low  = lane & 15;

    const int c  = blockIdx.x & 7;
    const int qb = (blockIdx.x >> 3) & 31;
    const int b  = blockIdx.x >> 8;

    const bf16* kbase = Kbuf + (long)b * T_LEN * HEAD;
    const bf16* vbase = Vt + (long)b * HEAD * T_LEN;

    // Q fragments (A-layout) direct: row qb*64+wave*16+low, k = quad*8 (+32)
    const bf16* qrow = kbase + (qb * 64 + wave * 16 + low) * HEAD + quad * 8;
    const bf16x8 qf0 = *(const bf16x8*)(qrow);
    const bf16x8 qf1 = *(const bf16x8*)(qrow + 32);

    bf16x8 ones;
#pragma unroll
    for (int i = 0; i < 8; ++i) ones[i] = (bf16)1.0f;

    floatx4 o[4], ol;
#pragma unroll
    for (int nt = 0; nt < 4; ++nt) o[nt] = (floatx4){0.f, 0.f, 0.f, 0.f};
    ol = (floatx4){0.f, 0.f, 0.f, 0.f};

    for (int j = c; j <= qb; j += 8) {
        // S = Q K^T : K-frag B[n=kv local][k=h] = Kbuf[(j*64 + nt*16+low)][quad*8+jj]
        const bf16* kr = kbase + (j * 64 + low) * HEAD + quad * 8;
        floatx4 s_[4];
#pragma unroll
        for (int nt = 0; nt < 4; ++nt) {
            bf16x8 kf0 = *(const bf16x8*)(kr + nt * 16 * HEAD);
            bf16x8 kf1 = *(const bf16x8*)(kr + nt * 16 * HEAD + 32);
            floatx4 z = (floatx4){0.f, 0.f, 0.f, 0.f};
            z = __builtin_amdgcn_mfma_f32_16x16x32_bf16(qf0, kf0, z, 0, 0, 0);
            z = __builtin_amdgcn_mfma_f32_16x16x32_bf16(qf1, kf1, z, 0, 0, 0);
            s_[nt] = z;
        }

        // p = exp2(s * 0.125*log2e); causal mask on diagonal tile; write P strip (C-layout)
        const bool diag = (j == qb);
#pragma unroll
        for (int nt = 0; nt < 4; ++nt) {
#pragma unroll
            for (int r = 0; r < 4; ++r) {
                float p = __builtin_amdgcn_exp2f(s_[nt][r] * 0.180336880f);
                if (diag && (nt * 16 + low) > (wave * 16 + quad * 4 + r)) p = 0.f;
                Ps[wave][quad * 4 + r][nt * 16 + low] = (bf16)p;
            }
        }

        // read P back in A-layout (wave-private: compiler's lgkmcnt ordering suffices)
        bf16x8 pf0 = *(const bf16x8*)&Ps[wave][low][quad * 8];
        bf16x8 pf1 = *(const bf16x8*)&Ps[wave][low][32 + quad * 8];

        // O += P V : V-frag B[n=h][k=kv] = Vt[nt*16+low][j*64 + quad*8 (+32)]
        const bf16* vr = vbase + (long)low * T_LEN + j * 64 + quad * 8;
#pragma unroll
        for (int nt = 0; nt < 4; ++nt) {
            bf16x8 vf0 = *(const bf16x8*)(vr + (long)nt * 16 * T_LEN);
            bf16x8 vf1 = *(const bf16x8*)(vr + (long)nt * 16 * T_LEN + 32);
            o[nt] = __builtin_amdgcn_mfma_f32_16x16x32_bf16(pf0, vf0, o[nt], 0, 0, 0);
            o[nt] = __builtin_amdgcn_mfma_f32_16x16x32_bf16(pf1, vf1, o[nt], 0, 0, 0);
        }
        ol = __builtin_amdgcn_mfma_f32_16x16x32_bf16(pf0, ones, ol, 0, 0, 0);
        ol = __builtin_amdgcn_mfma_f32_16x16x32_bf16(pf1, ones, ol, 0, 0, 0);
    }

    // write partials (zeros if no work)
    float* ob = Opart + (long)blockIdx.x * 4096;
#pragma unroll
    for (int nt = 0; nt < 4; ++nt) {
#pragma unroll
        for (int r = 0; r < 4; ++r) {
            int row = wave * 16 + quad * 4 + r;
            ob[row * 64 + nt * 16 + low] = o[nt][r];
        }
    }
    if (low == 0) {
#pragma unroll
        for (int r = 0; r < 4; ++r)
            lpart[(long)blockIdx.x * 64 + wave * 16 + quad * 4 + r] = ol[r];
    }
}

// ---------------- Kernel 3: combine 8 chunks. out = sum_c Opart / sum_c lpart.
__global__ __launch_bounds__(256) void attn_combine(const float* __restrict__ Opart,
                                                    const float* __restrict__ lpart,
                                                    float* __restrict__ out) {
    const int tile = blockIdx.x;         // 256 = b*32+qb
    const int tid  = threadIdx.x;
    const int row  = tid >> 2;           // 0..63
    const int col0 = (tid & 3) * 16;

    const float* ob = Opart + (long)tile * 8 * 4096 + row * 64 + col0;
    const float* lb = lpart + (long)tile * 8 * 64 + row;

    float l = 0.f;
#pragma unroll
    for (int ch = 0; ch < 8; ++ch) l += lb[ch * 64];
    float rl = 1.0f / l;

    float4 s0 = (float4){0.f, 0.f, 0.f, 0.f}, s1 = s0, s2 = s0, s3 = s0;
#pragma unroll
    for (int ch = 0; ch < 8; ++ch) {
        const float4* p = (const float4*)(ob + ch * 4096);
        float4 a = p[0], b = p[1], c = p[2], d = p[3];
        s0.x += a.x; s0.y += a.y; s0.z += a.z; s0.w += a.w;
        s1.x += b.x; s1.y += b.y; s1.z += b.z; s1.w += b.w;
        s2.x += c.x; s2.y += c.y; s2.z += c.z; s2.w += c.w;
        s3.x += d.x; s3.y += d.y; s3.z += d.z; s3.w += d.w;
    }
    s0.x *= rl; s0.y *= rl; s0.z *= rl; s0.w *= rl;
    s1.x *= rl; s1.y *= rl; s1.z *= rl; s1.w *= rl;
    s2.x *= rl; s2.y *= rl; s2.z *= rl; s2.w *= rl;
    s3.x *= rl; s3.y *= rl; s3.z *= rl; s3.w *= rl;

    float4* op = (float4*)(out + (long)tile * 4096 + row * 64 + col0);
    op[0] = s0; op[1] = s1; op[2] = s2; op[3] = s3;
}

extern "C" void kernel_launch(void* const* d_in, const int* in_sizes, int n_in,
                              void* d_out, int out_size, void* d_ws, size_t ws_size,
                              hipStream_t stream) {
    const float* x  = (const float*)d_in[0];
    const float* Wk = (const float*)d_in[1];
    const float* Wv = (const float*)d_in[2];
    float* out = (float*)d_out;

    char* ws = (char*)d_ws;
    bf16*  Wb    = (bf16*)ws;                           // 256 KB
    bf16*  Kbuf  = (bf16*)(ws + (1 << 20));             // 2 MB
    bf16*  Vt    = (bf16*)(ws + (3 << 20));             // 2 MB
    float* Opart = (float*)(ws + (5 << 20));            // 2048*4096*4 = 32 MB
    float* lpart = (float*)(ws + (37 << 20));           // 512 KB

    wconv_kernel<<<128, 256, 0, stream>>>(Wk, Wv, Wb);
    proj_kernel<<<512, 256, 0, stream>>>(x, Wb, Kbuf, Vt);
    attn_kernel<<<2048, 256, 0, stream>>>(Kbuf, Vt, Opart, lpart);
    attn_combine<<<256, 256, 0, stream>>>(Opart, lpart, out);
}

// Round 6
// 129.431 us; speedup vs baseline: 1.4765x; 1.4765x over previous
//
#include <hip/hip_runtime.h>

// Head: k = x@Wk^T; q = k (source bug); wei = softmax(causal(q k^T / 8)); v = x@Wv^T; out = wei@v
// B=8, T=2048, C=1024, H=64. fp32 in/out, bf16 MFMA internally.
//
// R5 -> R6: direct-global fragment loads were transaction-bound (16-32 lines/instr).
// Back to coalesced LDS staging (R4) with: depth-2 register prefetch (loads issued a
// full iteration ahead), LDS-transpose epilogues (coalesced 16B stores instead of
// 16 scalar 2B stores), attn split 8->4 with bf16 partials (Opart 32->8 MB).

typedef __bf16 bf16;
typedef __bf16 bf16x4 __attribute__((ext_vector_type(4)));
typedef __bf16 bf16x8 __attribute__((ext_vector_type(8)));
typedef float  floatx4 __attribute__((ext_vector_type(4)));

#define T_LEN 2048
#define HEAD  64
#define CEMB  1024

static __device__ __forceinline__ bf16x8 cvt2(float4 a, float4 b) {
    bf16x8 r;
    r[0] = (bf16)a.x; r[1] = (bf16)a.y; r[2] = (bf16)a.z; r[3] = (bf16)a.w;
    r[4] = (bf16)b.x; r[5] = (bf16)b.y; r[6] = (bf16)b.z; r[7] = (bf16)b.w;
    return r;
}

// ---------------- Kernel 0: W fp32 -> bf16, [Wk;Wv] concat as Wb[128][1024]
__global__ __launch_bounds__(256) void wconv_kernel(const float* __restrict__ Wk,
                                                    const float* __restrict__ Wv,
                                                    bf16* __restrict__ Wb) {
    int i = (blockIdx.x * 256 + threadIdx.x) * 4;   // grid 128 covers 131072
    const float* src = (i < 64 * 1024) ? (Wk + i) : (Wv + (i - 64 * 1024));
    float4 f = *(const float4*)src;
    bf16x4 v;
    v[0] = (bf16)f.x; v[1] = (bf16)f.y; v[2] = (bf16)f.z; v[3] = (bf16)f.w;
    *(bf16x4*)&Wb[i] = v;
}

// ---------------- Kernel 1: projection GEMM. grid 512, tile 32 rows x 128 cols, BK=64.
// Double-buffered LDS + depth-2 register prefetch (one barrier per K-step).
__global__ __launch_bounds__(256) void proj_kernel(const float* __restrict__ x,
                                                   const bf16* __restrict__ Wb,
                                                   bf16* __restrict__ Kbuf,
                                                   bf16* __restrict__ Vt) {
    __shared__ __align__(16) bf16 As[2][32][72];
    __shared__ __align__(16) bf16 Bs[2][128][72];

    const int tid  = threadIdx.x;
    const int wave = tid >> 6;
    const int lane = tid & 63;
    const int quad = lane >> 4;
    const int low  = lane & 15;

    const long row0 = (long)blockIdx.x * 32;

    const int a_row = tid >> 3;          // 0..31, 8 fp32/thread
    const int a_col = (tid & 7) * 8;
    const int b_row = tid >> 1;          // 0..127, 32 bf16/thread
    const int b_col = (tid & 1) * 32;

    const float* abase = x + (row0 + a_row) * CEMB + a_col;
    const bf16*  bbase = Wb + b_row * CEMB + b_col;

    const int strip = wave & 1;          // 16-row M strip
    const int nhalf = wave >> 1;         // 0 -> K n-tiles, 1 -> V n-tiles
    const int nq    = nhalf * 4;

    floatx4 acc[4];
#pragma unroll
    for (int i = 0; i < 4; ++i) acc[i] = (floatx4){0.f, 0.f, 0.f, 0.f};

    float4 apf[2][2];
    bf16x8 bpf[2][4];

    // prologue: load step0 -> set0, store to LDS0; load step1 -> set1
    apf[0][0] = ((const float4*)abase)[0];
    apf[0][1] = ((const float4*)abase)[1];
#pragma unroll
    for (int i = 0; i < 4; ++i) bpf[0][i] = *(const bf16x8*)(bbase + 8 * i);
    *(bf16x8*)&As[0][a_row][a_col] = cvt2(apf[0][0], apf[0][1]);
#pragma unroll
    for (int i = 0; i < 4; ++i) *(bf16x8*)&Bs[0][b_row][b_col + 8 * i] = bpf[0][i];
    apf[1][0] = ((const float4*)(abase + 64))[0];
    apf[1][1] = ((const float4*)(abase + 64))[1];
#pragma unroll
    for (int i = 0; i < 4; ++i) bpf[1][i] = *(const bf16x8*)(bbase + 64 + 8 * i);
    __syncthreads();

    int buf = 0;
    for (int s = 0; s < 16; ++s) {
        // store step s+1 (held in set (s+1)&1) into the alternate buffer
        if (s < 15) {
            const int q  = (s + 1) & 1;
            const int nb = buf ^ 1;
            *(bf16x8*)&As[nb][a_row][a_col] = cvt2(apf[q][0], apf[q][1]);
#pragma unroll
            for (int i = 0; i < 4; ++i) *(bf16x8*)&Bs[nb][b_row][b_col + 8 * i] = bpf[q][i];
        }
        // issue loads for step s+2 into the now-free set (s&1): a full iter of latency cover
        if (s < 14) {
            const int q  = s & 1;
            const int k0 = (s + 2) * 64;
            apf[q][0] = ((const float4*)(abase + k0))[0];
            apf[q][1] = ((const float4*)(abase + k0))[1];
#pragma unroll
            for (int i = 0; i < 4; ++i) bpf[q][i] = *(const bf16x8*)(bbase + k0 + 8 * i);
        }
        // compute current step from LDS[buf]
#pragma unroll
        for (int ks = 0; ks < 2; ++ks) {
            bf16x8 afrag = *(const bf16x8*)&As[buf][strip * 16 + low][ks * 32 + quad * 8];
#pragma unroll
            for (int i = 0; i < 4; ++i) {
                bf16x8 bfrag = *(const bf16x8*)&Bs[buf][(nq + i) * 16 + low][ks * 32 + quad * 8];
                acc[i] = __builtin_amdgcn_mfma_f32_16x16x32_bf16(afrag, bfrag, acc[i], 0, 0, 0);
            }
        }
        if (s < 15) {
            __syncthreads();
            buf ^= 1;
        }
    }

    // epilogue via LDS transpose (alias retired Bs): coalesced 16B stores.
    __syncthreads();
    bf16* Ek = (bf16*)&Bs[0][0][0];   // [32][72]: Ek[t][h]
    bf16* Ev = (bf16*)&Bs[1][0][0];   // [64][36]: Ev[h][t] (stride 36 -> 2-way bank alias)
    if (nhalf == 0) {
#pragma unroll
        for (int i = 0; i < 4; ++i)
#pragma unroll
            for (int r = 0; r < 4; ++r)
                Ek[(strip * 16 + quad * 4 + r) * 72 + i * 16 + low] = (bf16)acc[i][r];
    } else {
#pragma unroll
        for (int i = 0; i < 4; ++i)
#pragma unroll
            for (int r = 0; r < 4; ++r)
                Ev[(i * 16 + low) * 36 + strip * 16 + quad * 4 + r] = (bf16)acc[i][r];
    }
    __syncthreads();

    const long bidx  = row0 >> 11;
    const int  tloc0 = (int)(row0 & 2047);
    {   // K copy: thread t=tid>>3 (0..31), h0=(tid&7)*8 -> 16B contiguous, fully coalesced
        const int t  = tid >> 3;
        const int h0 = (tid & 7) * 8;
        *(bf16x8*)&Kbuf[(bidx * T_LEN + tloc0 + t) * HEAD + h0] = *(const bf16x8*)&Ek[t * 72 + h0];
    }
    {   // V copy: thread h=tid>>2 (0..63), t0=(tid&3)*8 -> 16B contiguous per h-row
        const int h  = tid >> 2;
        const int t0 = (tid & 3) * 8;
        *(bf16x8*)&Vt[(bidx * HEAD + h) * T_LEN + tloc0 + t0] = *(const bf16x8*)&Ev[h * 36 + t0];
    }
}

// ---------------- Kernel 2: attention partial. q=k, causal, scale 1/8, fixed-max softmax.
// blockIdx.x = ((b*32 + qb)*4 + c); chunk c: kv tiles j in {c, c+4, ...} <= qb (max 8 iters).
// K/V LDS double-buffered (1 barrier/iter); Q frags direct from global; bf16 partials.
__global__ __launch_bounds__(256) void attn_kernel(const bf16* __restrict__ Kbuf,
                                                   const bf16* __restrict__ Vt,
                                                   bf16* __restrict__ Opart,
                                                   float* __restrict__ lpart) {
    __shared__ __align__(16) bf16 Ks[2][64][72];
    __shared__ __align__(16) bf16 Vs[2][64][72];   // [h][kv]
    __shared__ __align__(16) bf16 Ps[4][16][72];   // per-wave private

    const int tid  = threadIdx.x;
    const int wave = tid >> 6;
    const int lane = tid & 63;
    const int quad = lane >> 4;
    const int low  = lane & 15;

    const int c  = blockIdx.x & 3;
    const int qb = (blockIdx.x >> 2) & 31;
    const int b  = blockIdx.x >> 7;

    const bf16* kbase = Kbuf + (long)b * T_LEN * HEAD;
    const bf16* vbase = Vt + (long)b * HEAD * T_LEN;

    // Q fragments (A-layout) direct from global (once per block)
    const bf16* qrow = kbase + (qb * 64 + wave * 16 + low) * HEAD + quad * 8;
    const bf16x8 qf0 = *(const bf16x8*)(qrow);
    const bf16x8 qf1 = *(const bf16x8*)(qrow + 32);

    bf16x8 ones;
#pragma unroll
    for (int i = 0; i < 8; ++i) ones[i] = (bf16)1.0f;

    floatx4 o[4], ol;
#pragma unroll
    for (int nt = 0; nt < 4; ++nt) o[nt] = (floatx4){0.f, 0.f, 0.f, 0.f};
    ol = (floatx4){0.f, 0.f, 0.f, 0.f};

    const int s_row = tid >> 2;          // 0..63
    const int s_col = (tid & 3) * 16;
    const bf16* ksrc = kbase + s_row * HEAD + s_col;
    const bf16* vsrc = vbase + (long)s_row * T_LEN + s_col;

    if (c <= qb) {
        // prologue: stage tile j=c into buf 0
        float4 kpf0 = *(const float4*)(ksrc + c * 4096);
        float4 kpf1 = *(const float4*)(ksrc + c * 4096 + 8);
        float4 vpf0 = *(const float4*)(vsrc + c * 64);
        float4 vpf1 = *(const float4*)(vsrc + c * 64 + 8);
        *(float4*)&Ks[0][s_row][s_col]     = kpf0;
        *(float4*)&Ks[0][s_row][s_col + 8] = kpf1;
        *(float4*)&Vs[0][s_row][s_col]     = vpf0;
        *(float4*)&Vs[0][s_row][s_col + 8] = vpf1;
        __syncthreads();

        int buf = 0;
        for (int j = c; j <= qb; j += 4) {
            const bool more = (j + 4 <= qb);
            if (more) {   // prefetch next tile (in flight during compute)
                kpf0 = *(const float4*)(ksrc + (j + 4) * 4096);
                kpf1 = *(const float4*)(ksrc + (j + 4) * 4096 + 8);
                vpf0 = *(const float4*)(vsrc + (j + 4) * 64);
                vpf1 = *(const float4*)(vsrc + (j + 4) * 64 + 8);
            }

            // S = Q K^T ; per-wave S tile [16 x 64]
            floatx4 s_[4];
#pragma unroll
            for (int nt = 0; nt < 4; ++nt) {
                bf16x8 kf0 = *(const bf16x8*)&Ks[buf][nt * 16 + low][quad * 8];
                bf16x8 kf1 = *(const bf16x8*)&Ks[buf][nt * 16 + low][32 + quad * 8];
                floatx4 z = (floatx4){0.f, 0.f, 0.f, 0.f};
                z = __builtin_amdgcn_mfma_f32_16x16x32_bf16(qf0, kf0, z, 0, 0, 0);
                z = __builtin_amdgcn_mfma_f32_16x16x32_bf16(qf1, kf1, z, 0, 0, 0);
                s_[nt] = z;
            }

            // p = exp2(s * 0.125*log2e); causal mask on diagonal tile; P strip -> LDS
            const bool diag = (j == qb);
#pragma unroll
            for (int nt = 0; nt < 4; ++nt) {
#pragma unroll
                for (int r = 0; r < 4; ++r) {
                    float p = __builtin_amdgcn_exp2f(s_[nt][r] * 0.180336880f);
                    if (diag && (nt * 16 + low) > (wave * 16 + quad * 4 + r)) p = 0.f;
                    Ps[wave][quad * 4 + r][nt * 16 + low] = (bf16)p;
                }
            }

            // O += P V ; l += P . ones  (Ps wave-private: lgkmcnt ordering suffices)
            bf16x8 pf0 = *(const bf16x8*)&Ps[wave][low][quad * 8];
            bf16x8 pf1 = *(const bf16x8*)&Ps[wave][low][32 + quad * 8];
#pragma unroll
            for (int nt = 0; nt < 4; ++nt) {
                bf16x8 vf0 = *(const bf16x8*)&Vs[buf][nt * 16 + low][quad * 8];
                bf16x8 vf1 = *(const bf16x8*)&Vs[buf][nt * 16 + low][32 + quad * 8];
                o[nt] = __builtin_amdgcn_mfma_f32_16x16x32_bf16(pf0, vf0, o[nt], 0, 0, 0);
                o[nt] = __builtin_amdgcn_mfma_f32_16x16x32_bf16(pf1, vf1, o[nt], 0, 0, 0);
            }
            ol = __builtin_amdgcn_mfma_f32_16x16x32_bf16(pf0, ones, ol, 0, 0, 0);
            ol = __builtin_amdgcn_mfma_f32_16x16x32_bf16(pf1, ones, ol, 0, 0, 0);

            if (more) {   // store prefetch to alternate buffer; single barrier
                const int nb = buf ^ 1;
                *(float4*)&Ks[nb][s_row][s_col]     = kpf0;
                *(float4*)&Ks[nb][s_row][s_col + 8] = kpf1;
                *(float4*)&Vs[nb][s_row][s_col]     = vpf0;
                *(float4*)&Vs[nb][s_row][s_col + 8] = vpf1;
                __syncthreads();
                buf = nb;
            }
        }
    }

    // epilogue via LDS transpose (alias retired Ks[0]): coalesced bf16 partial stores
    __syncthreads();
    bf16* Eo = (bf16*)&Ks[0][0][0];   // [64][72]: Eo[row][h]
#pragma unroll
    for (int nt = 0; nt < 4; ++nt)
#pragma unroll
        for (int r = 0; r < 4; ++r)
            Eo[(wave * 16 + quad * 4 + r) * 72 + nt * 16 + low] = (bf16)o[nt][r];
    __syncthreads();
    {
        const int row  = tid >> 2;
        const int col0 = (tid & 3) * 16;
        bf16* ob = Opart + (long)blockIdx.x * 4096 + row * 64 + col0;
        *(bf16x8*)(ob)     = *(const bf16x8*)&Eo[row * 72 + col0];
        *(bf16x8*)(ob + 8) = *(const bf16x8*)&Eo[row * 72 + col0 + 8];
    }
    if (low == 0) {
#pragma unroll
        for (int r = 0; r < 4; ++r)
            lpart[(long)blockIdx.x * 64 + wave * 16 + quad * 4 + r] = ol[r];
    }
}

// ---------------- Kernel 3: combine 4 chunks. out = sum_c Opart / sum_c lpart.
__global__ __launch_bounds__(256) void attn_combine(const bf16* __restrict__ Opart,
                                                    const float* __restrict__ lpart,
                                                    float* __restrict__ out) {
    const int tile = blockIdx.x;         // 256 = b*32+qb
    const int tid  = threadIdx.x;
    const int row  = tid >> 2;           // 0..63
    const int col0 = (tid & 3) * 16;

    const bf16*  ob = Opart + (long)tile * 4 * 4096 + row * 64 + col0;
    const float* lb = lpart + (long)tile * 4 * 64 + row;

    float l = lb[0] + lb[64] + lb[128] + lb[192];
    float rl = 1.0f / l;

    float s[16];
#pragma unroll
    for (int i = 0; i < 16; ++i) s[i] = 0.f;
#pragma unroll
    for (int ch = 0; ch < 4; ++ch) {
        bf16x8 u0 = *(const bf16x8*)(ob + ch * 4096);
        bf16x8 u1 = *(const bf16x8*)(ob + ch * 4096 + 8);
#pragma unroll
        for (int i = 0; i < 8; ++i) { s[i] += (float)u0[i]; s[8 + i] += (float)u1[i]; }
    }
    float4* op = (float4*)(out + (long)tile * 4096 + row * 64 + col0);
#pragma unroll
    for (int v = 0; v < 4; ++v) {
        float4 w;
        w.x = s[v * 4 + 0] * rl; w.y = s[v * 4 + 1] * rl;
        w.z = s[v * 4 + 2] * rl; w.w = s[v * 4 + 3] * rl;
        op[v] = w;
    }
}

extern "C" void kernel_launch(void* const* d_in, const int* in_sizes, int n_in,
                              void* d_out, int out_size, void* d_ws, size_t ws_size,
                              hipStream_t stream) {
    const float* x  = (const float*)d_in[0];
    const float* Wk = (const float*)d_in[1];
    const float* Wv = (const float*)d_in[2];
    float* out = (float*)d_out;

    char* ws = (char*)d_ws;
    bf16*  Wb    = (bf16*)ws;                           // 256 KB
    bf16*  Kbuf  = (bf16*)(ws + (1 << 20));             // 2 MB
    bf16*  Vt    = (bf16*)(ws + (3 << 20));             // 2 MB
    bf16*  Opart = (bf16*)(ws + (5 << 20));             // 1024*4096*2 = 8 MB
    float* lpart = (float*)(ws + (13 << 20));           // 256 KB

    wconv_kernel<<<128, 256, 0, stream>>>(Wk, Wv, Wb);
    proj_kernel<<<512, 256, 0, stream>>>(x, Wb, Kbuf, Vt);
    attn_kernel<<<1024, 256, 0, stream>>>(Kbuf, Vt, Opart, lpart);
    attn_combine<<<256, 256, 0, stream>>>(Opart, lpart, out);
}